// Round 2
// baseline (916.937 us; speedup 1.0000x reference)
//
#include <hip/hip_runtime.h>
#include <math.h>

// CapsNet fused forward, v2. One block of 192 threads per image.
// Per d-slice: Phase A (conv1, half-row tasks, weights from LDS) ->
// Phase B (prim conv, 2-row x 6-col register tile per thread over 16
// channels, parity-split + shfl_xor combine, fold into dig_W accumulator).
// Epilogue: block reduce -> squash -> 10x16 dense -> softmax.

#define BLOCK 192
#define C1S 404   // c1 channel stride (400 + 4 pad): i*404 % 32 = 20i -> spreads banks

__global__ __launch_bounds__(BLOCK, 2) void capsnet_fused(
    const float* __restrict__ x,        // [B,1,28,28]
    const float* __restrict__ conv1_w,  // [256,1,9,9]
    const float* __restrict__ conv1_b,  // [256]
    const float* __restrict__ prim_w,   // [32,32,1,9,9]
    const float* __restrict__ prim_b,   // [32]
    const float* __restrict__ dig_W,    // [1152,8,16]
    const float* __restrict__ dig_Wb,   // [1152,16]
    const float* __restrict__ out_w,    // [10,10,16,1]
    const float* __restrict__ out_b,    // [10]
    float* __restrict__ out)            // [B,10]
{
    __shared__ __align__(16) float img[784];          // 28*28
    __shared__ __align__(16) float c1[32 * C1S];      // 51.7 KB
    __shared__ __align__(16) float wlds[32 * 81];     // conv1_w slice for this d
    __shared__ float red[16];
    __shared__ float lgts[10];

    const int b = blockIdx.x;
    const int t = threadIdx.x;

    // ---- load image + zero reduction buffer ----
    for (int j = t; j < 784; j += BLOCK) img[j] = x[b * 784 + j];
    if (t < 16) red[t] = 0.f;

    float part[16];
#pragma unroll
    for (int k = 0; k < 16; ++k) part[k] = 0.f;

    // ---- dig_Wb contribution: sum_n dig_Wb[n,dd] (192 = 16 dd x 12 chunks) ----
    {
        const int dd = t & 15, chunk = t >> 4;   // chunk 0..11, 96 n each
        float s = 0.f;
        for (int j = 0; j < 96; ++j) s += dig_Wb[(chunk * 96 + j) * 16 + dd];
#pragma unroll
        for (int k = 0; k < 16; ++k) if (k == dd) part[k] += s;
    }

    // ---- stage conv1_w slice for d=0 ----
    for (int j = t; j < 2592; j += BLOCK) {
        const int i = j / 81, r = j % 81;
        wlds[j] = conv1_w[(i * 8 + 0) * 81 + r];
    }
    __syncthreads();

    for (int d = 0; d < 8; ++d) {
        // ======== Phase A: conv1 slice (channels i*8+d), half-row tasks ========
        // tau: i = tau&31, half = (tau>>5)&1, y = tau>>6  (1280 tasks)
        for (int tau = t; tau < 1280; tau += BLOCK) {
            const int i = tau & 31, half = (tau >> 5) & 1, y = tau >> 6;
            const int x0 = half * 10;
            float acc[10];
#pragma unroll
            for (int xx = 0; xx < 10; ++xx) acc[xx] = 0.f;
            const float* wch = &wlds[i * 81];
            for (int ky = 0; ky < 9; ++ky) {
                const float* row = &img[(y + ky) * 28 + x0];
                float r[18];
#pragma unroll
                for (int j = 0; j < 18; ++j) r[j] = row[j];
                const float* wr = wch + ky * 9;
#pragma unroll
                for (int kx = 0; kx < 9; ++kx) {
                    const float w = wr[kx];
#pragma unroll
                    for (int xx = 0; xx < 10; ++xx)
                        acc[xx] = fmaf(r[xx + kx], w, acc[xx]);
                }
            }
            const float bias = conv1_b[i * 8 + d];
            float* dst = &c1[i * C1S + y * 20 + x0];
#pragma unroll
            for (int xx = 0; xx < 10; ++xx)
                dst[xx] = fmaxf(acc[xx] + bias, 0.f);
        }
        __syncthreads();   // c1 ready; wlds(d) fully consumed

        // ---- stage conv1_w slice for d+1 (overlaps Phase B) ----
        if (d < 7) {
            for (int j = t; j < 2592; j += BLOCK) {
                const int i = j / 81, r = j % 81;
                wlds[j] = conv1_w[(i * 8 + d + 1) * 81 + r];
            }
        }

        // ======== Phase B: prim conv, 2 output rows x 6 cols, 16 channels ========
        // t -> parity (channel i%2), hp (row pair), o (out channel)
        {
            const int parity = t & 1;
            const int hp = (t >> 1) % 3;       // output rows 2hp, 2hp+1
            const int o = t / 6;
            const int rbase = 4 * hp;          // input rows rbase .. rbase+10
            float acc[12];                     // [2 rows][6 cols]
#pragma unroll
            for (int k = 0; k < 12; ++k) acc[k] = 0.f;

            for (int ii = 0; ii < 16; ++ii) {
                const int i = 2 * ii + parity;
                const float* wbase = &prim_w[(o * 32 + i) * 81];
                const float* cbase = &c1[i * C1S + rbase * 20];
#pragma unroll
                for (int rr = 0; rr < 11; ++rr) {
                    float r[20];
                    const float4* prow = (const float4*)(cbase + rr * 20);
#pragma unroll
                    for (int m = 0; m < 5; ++m) {
                        float4 v = prow[m];
                        r[m * 4 + 0] = v.x; r[m * 4 + 1] = v.y;
                        r[m * 4 + 2] = v.z; r[m * 4 + 3] = v.w;
                    }
                    if (rr <= 8) {              // feeds output row h0 (ky = rr)
                        const float* w0 = wbase + rr * 9;
#pragma unroll
                        for (int kx = 0; kx < 9; ++kx) {
                            const float w = w0[kx];
#pragma unroll
                            for (int ww = 0; ww < 6; ++ww)
                                acc[ww] = fmaf(r[2 * ww + kx], w, acc[ww]);
                        }
                    }
                    if (rr >= 2) {              // feeds output row h0+1 (ky = rr-2)
                        const float* w1 = wbase + (rr - 2) * 9;
#pragma unroll
                        for (int kx = 0; kx < 9; ++kx) {
                            const float w = w1[kx];
#pragma unroll
                            for (int ww = 0; ww < 6; ++ww)
                                acc[6 + ww] = fmaf(r[2 * ww + kx], w, acc[6 + ww]);
                        }
                    }
                }
            }

            // combine channel parities (lane pairs)
#pragma unroll
            for (int k = 0; k < 12; ++k) acc[k] += __shfl_xor(acc[k], 1, 64);

            // fold this thread's output row (h = 2hp + parity) into dig_W acc
            const float pb = prim_b[o];
            const int h = 2 * hp + parity;
#pragma unroll
            for (int ww = 0; ww < 6; ++ww) {
                const float a = (parity == 0) ? acc[ww] : acc[6 + ww];
                const float val = fmaxf(a + pb, 0.f);
                const int n = o * 36 + ww * 6 + h;
                const float4* wd = (const float4*)&dig_W[n * 128 + d * 16];
#pragma unroll
                for (int m = 0; m < 4; ++m) {
                    float4 v = wd[m];
                    part[m * 4 + 0] = fmaf(val, v.x, part[m * 4 + 0]);
                    part[m * 4 + 1] = fmaf(val, v.y, part[m * 4 + 1]);
                    part[m * 4 + 2] = fmaf(val, v.z, part[m * 4 + 2]);
                    part[m * 4 + 3] = fmaf(val, v.w, part[m * 4 + 3]);
                }
            }
        }
        __syncthreads();   // c1 free for next Phase A; wlds(d+1) ready
    }

    // ---- block-wide reduction of part[16] ----
#pragma unroll
    for (int k = 0; k < 16; ++k) {
        float v = part[k];
        v += __shfl_down(v, 32, 64);
        v += __shfl_down(v, 16, 64);
        v += __shfl_down(v, 8, 64);
        v += __shfl_down(v, 4, 64);
        v += __shfl_down(v, 2, 64);
        v += __shfl_down(v, 1, 64);
        if ((t & 63) == 0) atomicAdd(&red[k], v);
    }
    __syncthreads();

    // ---- squash + 10x16 dense ----
    if (t < 10) {
        float S[16];
        float l2 = 0.f, l1 = 0.f;
#pragma unroll
        for (int k = 0; k < 16; ++k) {
            S[k] = red[k] * (1.f / 1152.f);
            l2 += S[k] * S[k];
            l1 += fabsf(S[k]);
        }
        l2 = sqrtf(l2);
        const float sc = l2 / (1.f + l2) / l1;
        float lg = out_b[t];
        for (int i2 = 0; i2 < 10; ++i2) {
            const float* wrow = &out_w[(t * 10 + i2) * 16];
#pragma unroll
            for (int k = 0; k < 16; ++k)
                lg = fmaf(S[k] * sc, wrow[k], lg);
        }
        lgts[t] = lg;
    }
    __syncthreads();

    // ---- softmax over 10 ----
    if (t < 10) {
        float mx = -1e30f;
#pragma unroll
        for (int o = 0; o < 10; ++o) mx = fmaxf(mx, lgts[o]);
        float sum = 0.f;
#pragma unroll
        for (int o = 0; o < 10; ++o) sum += expf(lgts[o] - mx);
        out[b * 10 + t] = expf(lgts[t] - mx) / sum;
    }
}

extern "C" void kernel_launch(void* const* d_in, const int* in_sizes, int n_in,
                              void* d_out, int out_size, void* d_ws, size_t ws_size,
                              hipStream_t stream) {
    const float* x       = (const float*)d_in[0];
    const float* conv1_w = (const float*)d_in[1];
    const float* conv1_b = (const float*)d_in[2];
    const float* prim_w  = (const float*)d_in[3];
    const float* prim_b  = (const float*)d_in[4];
    const float* dig_W   = (const float*)d_in[5];
    const float* dig_Wb  = (const float*)d_in[6];
    const float* out_w   = (const float*)d_in[7];
    const float* out_b   = (const float*)d_in[8];
    float* out = (float*)d_out;

    const int B = in_sizes[0] / 784;   // 512
    capsnet_fused<<<B, BLOCK, 0, stream>>>(x, conv1_w, conv1_b, prim_w, prim_b,
                                           dig_W, dig_Wb, out_w, out_b, out);
}

// Round 3
// 240.509 us; speedup vs baseline: 3.8125x; 3.8125x over previous
//
#include <hip/hip_runtime.h>
#include <math.h>

// CapsNet fused forward, v3: bf16 MFMA path.
// Kernel 1 (pre): convert conv1_w/prim_w to zero-padded bf16 [*, 96] in ws,
//                 zero S accumulator, compute colsum(dig_Wb) and OW=sum_i out_w.
// Kernel 2 (main): one block (128 thr = 2 waves) per (image b, depth d):
//   conv1 GEMM  M=32 ch x N=400 pos x K=96  -> c1 bf16 in LDS
//   prim  GEMM  M=32 o  x N=48  pos x K=3072 (k-split across 2 waves)
//   cross-wave reduce, ReLU, fold u*dig_W into part[16], atomicAdd into S[b].
// Kernel 3 (epi): per image: squash(S/1152 + colsum/1152), 10x16 dense, softmax.

typedef __attribute__((ext_vector_type(8))) short bf16x8;
typedef __attribute__((ext_vector_type(4))) float f32x4;

__device__ inline unsigned short f2bf(float f) {
    union { float f; unsigned u; } v; v.f = f;
    unsigned r = v.u + 0x7fff + ((v.u >> 16) & 1);   // RNE
    return (unsigned short)(r >> 16);
}

// ---------------- pre kernel ----------------
__global__ void caps_pre(const float* __restrict__ conv1_w,
                         const float* __restrict__ prim_w,
                         const float* __restrict__ dig_Wb,
                         const float* __restrict__ out_w,
                         float* __restrict__ S,              // [B*16]
                         float* __restrict__ colsum,         // [16]
                         float* __restrict__ OW,             // [160]
                         unsigned short* __restrict__ c1wp,  // [256*96]
                         unsigned short* __restrict__ pwp,   // [1024*96]
                         int B)
{
    const int t = threadIdx.x;
    if (blockIdx.x == 512) {
        __shared__ float cs[16];
        if (t < 16) cs[t] = 0.f;
        __syncthreads();
        {
            const int k = t & 15, g = t >> 4;        // 16 groups x 72 rows
            float s = 0.f;
            for (int j = 0; j < 72; ++j) s += dig_Wb[(g * 72 + j) * 16 + k];
            atomicAdd(&cs[k], s);
        }
        __syncthreads();
        if (t < 16) colsum[t] = cs[t];
        if (t >= 64 && t < 224) {                     // OW[o][k] = sum_i out_w[o][i][k]
            const int idx = t - 64, o = idx >> 4, k = idx & 15;
            float s = 0.f;
            for (int i = 0; i < 10; ++i) s += out_w[(o * 10 + i) * 16 + k];
            OW[idx] = s;
        }
        return;
    }
    const int tid = blockIdx.x * 256 + t;
    if (tid < 24576) {                                // conv1_w -> [256][96] bf16
        const int c = tid / 96, k = tid % 96;
        c1wp[tid] = (k < 81) ? f2bf(conv1_w[c * 81 + k]) : (unsigned short)0;
    } else if (tid < 122880) {                        // prim_w -> [1024][96] bf16
        const int j = tid - 24576, row = j / 96, k = j % 96;
        pwp[j] = (k < 81) ? f2bf(prim_w[row * 81 + k]) : (unsigned short)0;
    } else if (tid - 122880 < B * 16) {
        S[tid - 122880] = 0.f;
    }
}

// ---------------- main kernel ----------------
__global__ __launch_bounds__(128, 2) void caps_main(
    const float* __restrict__ x,
    const float* __restrict__ conv1_b,
    const float* __restrict__ prim_b,
    const float* __restrict__ dig_W,
    const unsigned short* __restrict__ c1wp,
    const unsigned short* __restrict__ pwp,
    float* __restrict__ S)
{
    __shared__ float img[788];
    __shared__ unsigned short c1u[32 * 404];   // [32 ch][400 pos + 4 pad]
    __shared__ unsigned short tabA[96];        // k -> 28*ky+kx (img offsets)
    __shared__ unsigned short tabB[96];        // k -> 20*ky+kx (c1 offsets)
    __shared__ float cb[32], pb[32];
    __shared__ f32x4 redbuf[6 * 64];           // cross-wave acc exchange

    const int b = blockIdx.x >> 3, d = blockIdx.x & 7;
    const int t = threadIdx.x;
    const int wave = t >> 6, lane = t & 63;
    const int quad = lane >> 4, l16 = lane & 15;

    for (int j = t; j < 788; j += 128) img[j] = (j < 784) ? x[b * 784 + j] : 0.f;
    if (t < 96) {
        const int ky = t / 9, kx = t - 9 * ky;
        tabA[t] = (t < 81) ? (unsigned short)(ky * 28 + kx) : (unsigned short)0;
        tabB[t] = (t < 81) ? (unsigned short)(ky * 20 + kx) : (unsigned short)0;
    }
    if (t >= 96 && t < 128) {
        cb[t - 96] = conv1_b[(t - 96) * 8 + d];
        pb[t - 96] = prim_b[t - 96];
    }
    c1u[(t >> 2) * 404 + 400 + (t & 3)] = 0;   // zero row pads
    __syncthreads();

    // ======== conv1 GEMM: D[ch 32][pos 400], K = 96 ========
    bf16x8 cwA[6];   // A-frags [mt][ks]
#pragma unroll
    for (int mt = 0; mt < 2; ++mt)
#pragma unroll
        for (int ks = 0; ks < 3; ++ks) {
            const int i = mt * 16 + l16;
            cwA[mt * 3 + ks] =
                *(const bf16x8*)&c1wp[(i * 8 + d) * 96 + ks * 32 + quad * 8];
        }

    for (int nt = wave; nt < 25; nt += 2) {
        const int pos = nt * 16 + l16;
        const int y = pos / 20, x0 = pos - 20 * y;
        const int pbase = y * 28 + x0;
        f32x4 acc0 = {0.f, 0.f, 0.f, 0.f}, acc1 = {0.f, 0.f, 0.f, 0.f};
#pragma unroll
        for (int ks = 0; ks < 3; ++ks) {
            const int kb = ks * 32 + quad * 8;
            union { unsigned u[4]; bf16x8 v; } bu;
#pragma unroll
            for (int r = 0; r < 4; ++r) {
                const int k0 = kb + 2 * r, k1 = k0 + 1;
                float f0 = img[pbase + tabA[k0]];
                float f1 = img[pbase + tabA[k1]];
                if (ks == 2) {                 // K padding 81..95
                    if (k0 >= 81) f0 = 0.f;
                    if (k1 >= 81) f1 = 0.f;
                }
                bu.u[r] = (unsigned)f2bf(f0) | ((unsigned)f2bf(f1) << 16);
            }
            acc0 = __builtin_amdgcn_mfma_f32_16x16x32_bf16(cwA[ks],     bu.v, acc0, 0, 0, 0);
            acc1 = __builtin_amdgcn_mfma_f32_16x16x32_bf16(cwA[3 + ks], bu.v, acc1, 0, 0, 0);
        }
#pragma unroll
        for (int r = 0; r < 4; ++r) {          // D[m=quad*4+r][n=l16]
            const int i0 = quad * 4 + r;
            c1u[i0 * 404 + pos]        = f2bf(fmaxf(acc0[r] + cb[i0],      0.f));
            c1u[(16 + i0) * 404 + pos] = f2bf(fmaxf(acc1[r] + cb[16 + i0], 0.f));
        }
    }
    __syncthreads();

    // ======== prim GEMM: D[o 32][pos36->48], K = 32ch x 96, k-split by wave ====
    int po[3]; bool nval[3];
#pragma unroll
    for (int nt = 0; nt < 3; ++nt) {
        const int n = nt * 16 + l16;
        const bool v = (n < 36);
        const int h = n / 6, w = n - 6 * h;
        po[nt] = v ? (40 * h + 2 * w) : 0;
        nval[nt] = v;
    }

    f32x4 pa[6];
#pragma unroll
    for (int q = 0; q < 6; ++q) pa[q] = (f32x4){0.f, 0.f, 0.f, 0.f};

    for (int ic = 0; ic < 16; ++ic) {
        const int i = wave * 16 + ic;          // this wave's input-channel
        const int cbase = i * 404;
        bf16x8 Af[6];                          // A-frags [mt][sub], prefetch
#pragma unroll
        for (int sub = 0; sub < 3; ++sub) {
            Af[sub]     = *(const bf16x8*)&pwp[(l16 * 32 + i) * 96 + sub * 32 + quad * 8];
            Af[3 + sub] = *(const bf16x8*)&pwp[((16 + l16) * 32 + i) * 96 + sub * 32 + quad * 8];
        }
#pragma unroll
        for (int sub = 0; sub < 3; ++sub) {
            const int kb = sub * 32 + quad * 8;
            unsigned short tv[8];
#pragma unroll
            for (int j = 0; j < 8; ++j) tv[j] = tabB[kb + j];   // quad-uniform -> broadcast
#pragma unroll
            for (int nt = 0; nt < 3; ++nt) {
                const int gb = cbase + po[nt];
                union { unsigned u[4]; bf16x8 v; } bu;
#pragma unroll
                for (int r = 0; r < 4; ++r) {
                    unsigned short u0 = c1u[gb + tv[2 * r]];
                    unsigned short u1 = c1u[gb + tv[2 * r + 1]];
                    if (sub == 2) {            // K padding 81..95
                        if (kb + 2 * r     >= 81) u0 = 0;
                        if (kb + 2 * r + 1 >= 81) u1 = 0;
                    }
                    bu.u[r] = (unsigned)u0 | ((unsigned)u1 << 16);
                }
                if (!nval[nt]) { bu.u[0] = bu.u[1] = bu.u[2] = bu.u[3] = 0; }
                pa[nt]     = __builtin_amdgcn_mfma_f32_16x16x32_bf16(Af[sub],     bu.v, pa[nt],     0, 0, 0);
                pa[3 + nt] = __builtin_amdgcn_mfma_f32_16x16x32_bf16(Af[3 + sub], bu.v, pa[3 + nt], 0, 0, 0);
            }
        }
    }
    __syncthreads();

    // ---- cross-wave k-reduction ----
    if (wave == 1) {
#pragma unroll
        for (int q = 0; q < 6; ++q) redbuf[q * 64 + lane] = pa[q];
    }
    __syncthreads();
    if (wave == 0) {
#pragma unroll
        for (int q = 0; q < 6; ++q) pa[q] += redbuf[q * 64 + lane];
#pragma unroll
        for (int q = 3; q < 6; ++q) redbuf[(q - 3) * 64 + lane] = pa[q];  // full u, tiles 3..5
    }
    __syncthreads();

    // ---- ReLU + fold u * dig_W ; wave0: m-tile 0, wave1: m-tile 1 ----
    float part[16];
#pragma unroll
    for (int k = 0; k < 16; ++k) part[k] = 0.f;

    const int mt = wave;
#pragma unroll
    for (int tl = 0; tl < 3; ++tl) {
        f32x4 u4 = (wave == 0) ? pa[tl] : redbuf[tl * 64 + lane];
        const int n = tl * 16 + l16;
        if (n < 36) {
            const int h = n / 6, w = n - 6 * h;
#pragma unroll
            for (int r = 0; r < 4; ++r) {
                const int o = mt * 16 + quad * 4 + r;
                const float val = fmaxf(u4[r] + pb[o], 0.f);
                const int ncaps = o * 36 + w * 6 + h;    // swapaxes(2,4) ordering
                const f32x4* wd = (const f32x4*)&dig_W[(ncaps * 8 + d) * 16];
#pragma unroll
                for (int m = 0; m < 4; ++m) {
                    f32x4 wv = wd[m];
                    part[m * 4 + 0] = fmaf(val, wv[0], part[m * 4 + 0]);
                    part[m * 4 + 1] = fmaf(val, wv[1], part[m * 4 + 1]);
                    part[m * 4 + 2] = fmaf(val, wv[2], part[m * 4 + 2]);
                    part[m * 4 + 3] = fmaf(val, wv[3], part[m * 4 + 3]);
                }
            }
        }
    }

#pragma unroll
    for (int k = 0; k < 16; ++k) {
        float v = part[k];
        v += __shfl_xor(v, 32, 64);
        v += __shfl_xor(v, 16, 64);
        v += __shfl_xor(v, 8, 64);
        v += __shfl_xor(v, 4, 64);
        v += __shfl_xor(v, 2, 64);
        v += __shfl_xor(v, 1, 64);
        part[k] = v;
    }
    if (lane == 0) {
#pragma unroll
        for (int k = 0; k < 16; ++k) atomicAdd(&S[b * 16 + k], part[k]);
    }
}

// ---------------- epilogue kernel ----------------
__global__ void caps_epi(const float* __restrict__ S, const float* __restrict__ colsum,
                         const float* __restrict__ OW, const float* __restrict__ out_b,
                         float* __restrict__ out, int B)
{
    const int b = blockIdx.x * 256 + threadIdx.x;
    if (b >= B) return;
    float Sv[16]; float l2 = 0.f, l1 = 0.f;
#pragma unroll
    for (int k = 0; k < 16; ++k) {
        const float s = (S[b * 16 + k] + colsum[k]) * (1.f / 1152.f);
        Sv[k] = s; l2 += s * s; l1 += fabsf(s);
    }
    l2 = sqrtf(l2);
    const float sc = l2 / (1.f + l2) / l1;
    float lg[10]; float mx = -1e30f;
#pragma unroll
    for (int o = 0; o < 10; ++o) {
        float a = out_b[o];
#pragma unroll
        for (int k = 0; k < 16; ++k) a = fmaf(Sv[k] * sc, OW[o * 16 + k], a);
        lg[o] = a; mx = fmaxf(mx, a);
    }
    float sum = 0.f;
#pragma unroll
    for (int o = 0; o < 10; ++o) { lg[o] = expf(lg[o] - mx); sum += lg[o]; }
    const float inv = 1.f / sum;
#pragma unroll
    for (int o = 0; o < 10; ++o) out[b * 10 + o] = lg[o] * inv;
}

extern "C" void kernel_launch(void* const* d_in, const int* in_sizes, int n_in,
                              void* d_out, int out_size, void* d_ws, size_t ws_size,
                              hipStream_t stream) {
    const float* x       = (const float*)d_in[0];
    const float* conv1_w = (const float*)d_in[1];
    const float* conv1_b = (const float*)d_in[2];
    const float* prim_w  = (const float*)d_in[3];
    const float* prim_b  = (const float*)d_in[4];
    const float* dig_W   = (const float*)d_in[5];
    const float* dig_Wb  = (const float*)d_in[6];
    const float* out_w   = (const float*)d_in[7];
    const float* out_b   = (const float*)d_in[8];
    float* out = (float*)d_out;

    const int B = in_sizes[0] / 784;   // 512

    char* w = (char*)d_ws;
    float* S            = (float*)(w);                  // B*16 f32
    float* colsum       = (float*)(w + 32768);          // 16 f32
    float* OW           = (float*)(w + 32832);          // 160 f32
    unsigned short* c1wp = (unsigned short*)(w + 33472);            // 256*96 bf16
    unsigned short* pwp  = (unsigned short*)(w + 33472 + 49152);    // 1024*96 bf16

    caps_pre<<<513, 256, 0, stream>>>(conv1_w, prim_w, dig_Wb, out_w,
                                      S, colsum, OW, c1wp, pwp, B);
    caps_main<<<B * 8, 128, 0, stream>>>(x, conv1_b, prim_b, dig_W, c1wp, pwp, S);
    caps_epi<<<(B + 255) / 256, 256, 0, stream>>>(S, colsum, OW, out_b, out, B);
}

// Round 4
// 221.366 us; speedup vs baseline: 4.1422x; 1.0865x over previous
//
#include <hip/hip_runtime.h>
#include <math.h>

// CapsNet fused forward, v4: vector-load MFMA fragments.
// pre : conv1_w -> c1wp2[256][96] bf16 (K-permuted: 36 even-x pairs, 9 solos, pad);
//       prim_w  -> pw2[81 tap][32 o][32 i] bf16; colsum(dig_Wb); OW=sum_i out_w; S=0.
// main: one block (128 thr) per (image, d-pair). Per d:
//       conv1 GEMM (m=pos 400, n=ch 32, K=96) -> c1t[pos][ch] bf16 (+16B skew/2rows)
//       A-frags from imgp bf16-pair gathers (mostly 1 ds_read_b32 per 2 taps).
//       prim GEMM: loop 81 taps, K=32 channels: B-frag = ds_read_b128 (2-way banks,
//       free), A-frag = global b128 from pw2 (L2). 12 MFMA / tap (2m x 3n x 2d).
//       Cross-wave tap-split reduce via LDS overlay, ReLU+fold u*dig_W, atomicAdd S.
// epi : squash((S+colsum)/1152), 10x16 dense, softmax.

typedef __attribute__((ext_vector_type(8))) short bf16x8;
typedef __attribute__((ext_vector_type(4))) float f32x4;

__device__ inline unsigned short f2bf(float f) {
    union { float f; unsigned u; } v; v.f = f;
    unsigned r = v.u + 0x7fff + ((v.u >> 16) & 1);   // RNE
    return (unsigned short)(r >> 16);
}

#define C1TN 16008   // u16 per c1t slice (400*40 + 8 skew pad)

// ---------------- pre kernel ----------------
__global__ void caps_pre(const float* __restrict__ conv1_w,
                         const float* __restrict__ prim_w,
                         const float* __restrict__ dig_Wb,
                         const float* __restrict__ out_w,
                         float* __restrict__ S,              // [B*16]
                         float* __restrict__ colsum,         // [16]
                         float* __restrict__ OW,             // [160]
                         unsigned short* __restrict__ c1wp2, // [256*96]
                         unsigned short* __restrict__ pw2,   // [81*1024]
                         int B)
{
    const int t = threadIdx.x;
    if (blockIdx.x == 452) {
        __shared__ float cs[16];
        if (t < 16) cs[t] = 0.f;
        __syncthreads();
        {
            const int k = t & 15, g = t >> 4;
            float s = 0.f;
            for (int j = 0; j < 72; ++j) s += dig_Wb[(g * 72 + j) * 16 + k];
            atomicAdd(&cs[k], s);
        }
        __syncthreads();
        if (t < 16) colsum[t] = cs[t];
        if (t >= 64 && t < 224) {
            const int idx = t - 64, o = idx >> 4, k = idx & 15;
            float s = 0.f;
            for (int i = 0; i < 10; ++i) s += out_w[(o * 10 + i) * 16 + k];
            OW[idx] = s;
        }
        return;
    }
    const int tid = blockIdx.x * 256 + t;
    if (tid < 24576) {                       // c1wp2, K-permuted
        const int c = tid / 96, kn = tid % 96;
        unsigned short v = 0;
        if (kn < 72) {
            const int p = kn >> 1, lo = kn & 1, ky = p >> 2, kx = 2 * (p & 3) + lo;
            v = f2bf(conv1_w[c * 81 + 9 * ky + kx]);
        } else if (kn < 81) {
            v = f2bf(conv1_w[c * 81 + 9 * (kn - 72) + 8]);
        }
        c1wp2[tid] = v;
    } else if (tid < 24576 + 82944) {        // pw2[tap][o][i]
        const int j = tid - 24576;
        const int t81 = j >> 10, rem = j & 1023, o = rem >> 5, i = rem & 31;
        pw2[j] = f2bf(prim_w[(o * 32 + i) * 81 + t81]);
    } else {
        const int k = tid - 107520;
        if (k < B * 16) S[k] = 0.f;
    }
}

// ---------------- main kernel ----------------
__global__ __launch_bounds__(128, 2) void caps_main(
    const float* __restrict__ x,
    const float* __restrict__ conv1_b,
    const float* __restrict__ prim_b,
    const float* __restrict__ dig_W,
    const unsigned short* __restrict__ c1wp2,
    const unsigned short* __restrict__ pw2,
    float* __restrict__ S)
{
    __shared__ __align__(16) unsigned short c1t[2 * C1TN];  // 64 KB (2 d-slices)
    __shared__ __align__(16) unsigned imgp[1344];           // bf16 pairs + zero pad
    __shared__ unsigned short offT[64];                     // byte offsets into imgp
    __shared__ float pbs[32];

    const int b = blockIdx.x >> 2, dp = blockIdx.x & 3;
    const int d0 = dp * 2;
    const int t = threadIdx.x;
    const int wave = t >> 6, lane = t & 63, quad = lane >> 4, l16 = lane & 15;

    // ---- imgp: packed bf16 pairs (img[y][x], img[y][x+1]), zero pad to 1344 ----
    const float* xb = x + b * 784;
    for (int j = t; j < 1344; j += 128) {
        unsigned v = 0;
        if (j < 784) {
            const float a = xb[j];
            const int xc = j - 28 * (int)(((unsigned)j * 37450u) >> 20);
            const float c = (xc < 27) ? xb[j + 1] : 0.f;
            v = (unsigned)f2bf(a) | ((unsigned)f2bf(c) << 16);
        }
        imgp[j] = v;
    }
    // ---- tap-offset tables (byte offsets, x4) ----
    if (t < 64) {
        int v;
        if (t < 32) {                         // pair region, ks0/ks1: p = t
            const int ky = t >> 2, kx = 2 * (t & 3);
            v = ky * 28 + kx;
        } else {                              // generic region, k = t + 32 (64..95)
            const int k = t + 32;
            if (k < 72) {
                const int p = k >> 1, lo = k & 1, ky = p >> 2, kx = 2 * (p & 3) + lo;
                v = ky * 28 + kx;
            } else if (k < 81) {
                v = (k - 72) * 28 + 8;
            } else v = 784;                   // zero-pad entry
        }
        offT[t] = (unsigned short)(4 * v);
    }
    if (t < 32) pbs[t] = prim_b[t];
    __syncthreads();

    // hoist per-lane tap byte-offsets
    unsigned tp0[4], tp1[4], t2a[4], t2b[4];
#pragma unroll
    for (int r = 0; r < 4; ++r) {
        tp0[r] = offT[quad * 4 + r];
        tp1[r] = offT[16 + quad * 4 + r];
        t2a[r] = offT[32 + quad * 8 + 2 * r];
        t2b[r] = offT[32 + quad * 8 + 2 * r + 1];
    }

    // ======== conv1 (both d-slices), m-split across waves ========
    const int mt_lo = wave ? 13 : 0, mt_hi = wave ? 25 : 13;
    for (int e = 0; e < 2; ++e) {
        const int d = d0 + e;
        unsigned short* dst = c1t + e * C1TN;
        const float cb0 = conv1_b[l16 * 8 + d];
        const float cb1 = conv1_b[(16 + l16) * 8 + d];
        bf16x8 Bw0[3], Bw1[3];
#pragma unroll
        for (int ks = 0; ks < 3; ++ks) {
            Bw0[ks] = *(const bf16x8*)&c1wp2[(l16 * 8 + d) * 96 + ks * 32 + quad * 8];
            Bw1[ks] = *(const bf16x8*)&c1wp2[((16 + l16) * 8 + d) * 96 + ks * 32 + quad * 8];
        }
        for (int mt = mt_lo; mt < mt_hi; ++mt) {
            const int pos = mt * 16 + l16;
            const int y = (int)(((unsigned)pos * 52429u) >> 20);
            const unsigned pb4 = (unsigned)(pos + 8 * y) * 4u;   // 4*(y*28+x)
            f32x4 a0 = {0.f, 0.f, 0.f, 0.f}, a1 = {0.f, 0.f, 0.f, 0.f};
            union { unsigned u[4]; bf16x8 v; } A;
#pragma unroll
            for (int r = 0; r < 4; ++r)
                A.u[r] = *(const unsigned*)((const char*)imgp + (pb4 + tp0[r]));
            a0 = __builtin_amdgcn_mfma_f32_16x16x32_bf16(A.v, Bw0[0], a0, 0, 0, 0);
            a1 = __builtin_amdgcn_mfma_f32_16x16x32_bf16(A.v, Bw1[0], a1, 0, 0, 0);
#pragma unroll
            for (int r = 0; r < 4; ++r)
                A.u[r] = *(const unsigned*)((const char*)imgp + (pb4 + tp1[r]));
            a0 = __builtin_amdgcn_mfma_f32_16x16x32_bf16(A.v, Bw0[1], a0, 0, 0, 0);
            a1 = __builtin_amdgcn_mfma_f32_16x16x32_bf16(A.v, Bw1[1], a1, 0, 0, 0);
#pragma unroll
            for (int r = 0; r < 4; ++r) {
                const unsigned lo = *(const unsigned*)((const char*)imgp + (pb4 + t2a[r]));
                const unsigned hi = *(const unsigned*)((const char*)imgp + (pb4 + t2b[r]));
                A.u[r] = (lo & 0xFFFFu) | (hi << 16);
            }
            a0 = __builtin_amdgcn_mfma_f32_16x16x32_bf16(A.v, Bw0[2], a0, 0, 0, 0);
            a1 = __builtin_amdgcn_mfma_f32_16x16x32_bf16(A.v, Bw1[2], a1, 0, 0, 0);
            // store D rows pos=mt*16+quad*4+r, cols ch=l16 / 16+l16
#pragma unroll
            for (int r = 0; r < 4; ++r) {
                const int pr = mt * 16 + quad * 4 + r;
                const int spar = (int)((((unsigned)pr * 52429u) >> 21) & 1u);
                const int base = pr * 40 + 8 * spar;
                dst[base + l16]      = f2bf(fmaxf(a0[r] + cb0, 0.f));
                dst[base + 16 + l16] = f2bf(fmaxf(a1[r] + cb1, 0.f));
            }
        }
    }
    __syncthreads();

    // ======== prim GEMM: K=32 ch per tap, 81 taps split by wave ========
    const int hp = l16 >> 3, wp = l16 & 7;               // n = 8h' + w'
    const unsigned Lbase = 80u * (unsigned)(40 * hp + 2 * wp) + 16u * quad;
    const unsigned Lh0 = Lbase + 16u * hp;               // kk=0: spar=hp
    const unsigned Lh1 = Lbase + 16u * (1 - hp);         // kk=1: spar=1-hp

    f32x4 pa[12];
#pragma unroll
    for (int q = 0; q < 12; ++q) pa[q] = (f32x4){0.f, 0.f, 0.f, 0.f};

    for (int off = wave; off < 81; off += 2) {
        const int ky = (off * 57) >> 9;
        const int kx = off - 9 * ky;
        const int kk = (ky >> 1) & 1;
        const unsigned soff = 80u * (unsigned)(20 * ky + kx);
        const unsigned ad = (kk ? Lh1 : Lh0) + soff;
        const char* b0 = (const char*)c1t + ad;
        const unsigned short* ap = &pw2[off * 1024 + l16 * 32 + quad * 8];
        const bf16x8 A0 = *(const bf16x8*)ap;
        const bf16x8 A1 = *(const bf16x8*)(ap + 512);
#pragma unroll
        for (int nt = 0; nt < 3; ++nt) {
            const bf16x8 Bf0 = *(const bf16x8*)(b0 + nt * 6400);
            const bf16x8 Bf1 = *(const bf16x8*)(b0 + nt * 6400 + 2 * C1TN);
            pa[nt]     = __builtin_amdgcn_mfma_f32_16x16x32_bf16(A0, Bf0, pa[nt],     0, 0, 0);
            pa[3 + nt] = __builtin_amdgcn_mfma_f32_16x16x32_bf16(A1, Bf0, pa[3 + nt], 0, 0, 0);
            pa[6 + nt] = __builtin_amdgcn_mfma_f32_16x16x32_bf16(A0, Bf1, pa[6 + nt], 0, 0, 0);
            pa[9 + nt] = __builtin_amdgcn_mfma_f32_16x16x32_bf16(A1, Bf1, pa[9 + nt], 0, 0, 0);
        }
    }
    __syncthreads();

    // ---- cross-wave tap-split reduction (redbuf overlays c1t) ----
    f32x4* redbuf = (f32x4*)c1t;
    {
        const int eo = 1 - wave;                   // export the other wave's d
#pragma unroll
        for (int q = 0; q < 6; ++q) redbuf[(wave * 6 + q) * 64 + lane] = pa[eo * 6 + q];
    }
    __syncthreads();
    const int e = wave, d = d0 + e;
    f32x4 full[6];
#pragma unroll
    for (int q = 0; q < 6; ++q) full[q] = pa[e * 6 + q] + redbuf[((1 - wave) * 6 + q) * 64 + lane];

    // ---- ReLU + fold u * dig_W ----
    float part[16];
#pragma unroll
    for (int k = 0; k < 16; ++k) part[k] = 0.f;

    if (wp < 6) {
#pragma unroll
        for (int mt = 0; mt < 2; ++mt)
#pragma unroll
            for (int nt = 0; nt < 3; ++nt) {
                const f32x4 u4 = full[mt * 3 + nt];
                const int h = 2 * nt + hp;
#pragma unroll
                for (int r = 0; r < 4; ++r) {
                    const int o = mt * 16 + quad * 4 + r;
                    const float val = fmaxf(u4[r] + pbs[o], 0.f);
                    const int nc = o * 36 + wp * 6 + h;
                    const f32x4* wd = (const f32x4*)&dig_W[(nc * 8 + d) * 16];
#pragma unroll
                    for (int m = 0; m < 4; ++m) {
                        const f32x4 wv = wd[m];
                        part[m * 4 + 0] = fmaf(val, wv[0], part[m * 4 + 0]);
                        part[m * 4 + 1] = fmaf(val, wv[1], part[m * 4 + 1]);
                        part[m * 4 + 2] = fmaf(val, wv[2], part[m * 4 + 2]);
                        part[m * 4 + 3] = fmaf(val, wv[3], part[m * 4 + 3]);
                    }
                }
            }
    }

#pragma unroll
    for (int k = 0; k < 16; ++k) {
        float v = part[k];
        v += __shfl_xor(v, 32, 64);
        v += __shfl_xor(v, 16, 64);
        v += __shfl_xor(v, 8, 64);
        v += __shfl_xor(v, 4, 64);
        v += __shfl_xor(v, 2, 64);
        v += __shfl_xor(v, 1, 64);
        part[k] = v;
    }
    if (lane == 0) {
#pragma unroll
        for (int k = 0; k < 16; ++k) atomicAdd(&S[b * 16 + k], part[k]);
    }
}

// ---------------- epilogue kernel ----------------
__global__ void caps_epi(const float* __restrict__ S, const float* __restrict__ colsum,
                         const float* __restrict__ OW, const float* __restrict__ out_b,
                         float* __restrict__ out, int B)
{
    const int b = blockIdx.x * 256 + threadIdx.x;
    if (b >= B) return;
    float Sv[16]; float l2 = 0.f, l1 = 0.f;
#pragma unroll
    for (int k = 0; k < 16; ++k) {
        const float s = (S[b * 16 + k] + colsum[k]) * (1.f / 1152.f);
        Sv[k] = s; l2 += s * s; l1 += fabsf(s);
    }
    l2 = sqrtf(l2);
    const float sc = l2 / (1.f + l2) / l1;
    float lg[10]; float mx = -1e30f;
#pragma unroll
    for (int o = 0; o < 10; ++o) {
        float a = out_b[o];
#pragma unroll
        for (int k = 0; k < 16; ++k) a = fmaf(Sv[k] * sc, OW[o * 16 + k], a);
        lg[o] = a; mx = fmaxf(mx, a);
    }
    float sum = 0.f;
#pragma unroll
    for (int o = 0; o < 10; ++o) { lg[o] = expf(lg[o] - mx); sum += lg[o]; }
    const float inv = 1.f / sum;
#pragma unroll
    for (int o = 0; o < 10; ++o) out[b * 10 + o] = lg[o] * inv;
}

extern "C" void kernel_launch(void* const* d_in, const int* in_sizes, int n_in,
                              void* d_out, int out_size, void* d_ws, size_t ws_size,
                              hipStream_t stream) {
    const float* x       = (const float*)d_in[0];
    const float* conv1_w = (const float*)d_in[1];
    const float* conv1_b = (const float*)d_in[2];
    const float* prim_w  = (const float*)d_in[3];
    const float* prim_b  = (const float*)d_in[4];
    const float* dig_W   = (const float*)d_in[5];
    const float* dig_Wb  = (const float*)d_in[6];
    const float* out_w   = (const float*)d_in[7];
    const float* out_b   = (const float*)d_in[8];
    float* out = (float*)d_out;

    const int B = in_sizes[0] / 784;   // 512

    char* w = (char*)d_ws;
    float* S              = (float*)(w);                 // 32768 B
    float* colsum         = (float*)(w + 32768);
    float* OW             = (float*)(w + 32832);
    unsigned short* c1wp2 = (unsigned short*)(w + 33472);            // 49152 B
    unsigned short* pw2   = (unsigned short*)(w + 33472 + 49152);    // 165888 B

    caps_pre<<<453, 256, 0, stream>>>(conv1_w, prim_w, dig_Wb, out_w,
                                      S, colsum, OW, c1wp2, pw2, B);
    caps_main<<<B * 4, 128, 0, stream>>>(x, conv1_b, prim_b, dig_W, c1wp2, pw2, S);
    caps_epi<<<(B + 255) / 256, 256, 0, stream>>>(S, colsum, OW, out_b, out, B);
}

// Round 5
// 182.148 us; speedup vs baseline: 5.0340x; 1.2153x over previous
//
#include <hip/hip_runtime.h>
#include <math.h>

// CapsNet fused forward, v5: v4 structure + 4 waves/block + pipelined A-loads.
// pre : conv1_w -> c1wp2[256][96] bf16 (K-permuted); prim_w -> pw2[85][32o][32i]
//       bf16 (taps 81..84 zero, prefetch pad); colsum(dig_Wb); OW; S=0.
// main: one block (256 thr = 4 waves) per (image, d-pair).
//       conv1: waves 0,1 -> d0, waves 2,3 -> d0+1; mt parity split.
//       prim : taps stride-4 across waves, A-frags prefetched 1 iter ahead,
//              B-frag = ds_read_b128 from c1t (skewed, 2-way banks = free).
//       4-wave tap reduction via LDS overlay; waves 0,1 fold u*dig_W (d0,d0+1).
// epi : squash((S+colsum)/1152), 10x16 dense, softmax.

typedef __attribute__((ext_vector_type(8))) short bf16x8;
typedef __attribute__((ext_vector_type(4))) float f32x4;

__device__ inline unsigned short f2bf(float f) {
    union { float f; unsigned u; } v; v.f = f;
    unsigned r = v.u + 0x7fff + ((v.u >> 16) & 1);   // RNE
    return (unsigned short)(r >> 16);
}

#define C1TN 16008   // u16 per c1t slice (400*40 + 8 skew pad)

// ---------------- pre kernel ----------------
__global__ void caps_pre(const float* __restrict__ conv1_w,
                         const float* __restrict__ prim_w,
                         const float* __restrict__ dig_Wb,
                         const float* __restrict__ out_w,
                         float* __restrict__ S,              // [B*16]
                         float* __restrict__ colsum,         // [16]
                         float* __restrict__ OW,             // [160]
                         unsigned short* __restrict__ c1wp2, // [256*96]
                         unsigned short* __restrict__ pw2,   // [85*1024]
                         int B)
{
    const int t = threadIdx.x;
    if (blockIdx.x == 468) {
        __shared__ float cs[16];
        if (t < 16) cs[t] = 0.f;
        __syncthreads();
        {
            const int k = t & 15, g = t >> 4;
            float s = 0.f;
            for (int j = 0; j < 72; ++j) s += dig_Wb[(g * 72 + j) * 16 + k];
            atomicAdd(&cs[k], s);
        }
        __syncthreads();
        if (t < 16) colsum[t] = cs[t];
        if (t >= 64 && t < 224) {
            const int idx = t - 64, o = idx >> 4, k = idx & 15;
            float s = 0.f;
            for (int i = 0; i < 10; ++i) s += out_w[(o * 10 + i) * 16 + k];
            OW[idx] = s;
        }
        return;
    }
    const int tid = blockIdx.x * 256 + t;
    if (tid < 24576) {                       // c1wp2, K-permuted
        const int c = tid / 96, kn = tid % 96;
        unsigned short v = 0;
        if (kn < 72) {
            const int p = kn >> 1, lo = kn & 1, ky = p >> 2, kx = 2 * (p & 3) + lo;
            v = f2bf(conv1_w[c * 81 + 9 * ky + kx]);
        } else if (kn < 81) {
            v = f2bf(conv1_w[c * 81 + 9 * (kn - 72) + 8]);
        }
        c1wp2[tid] = v;
    } else if (tid < 24576 + 87040) {        // pw2[tap 0..84][o][i], 81..84 zero
        const int j = tid - 24576;
        const int t81 = j >> 10, rem = j & 1023, o = rem >> 5, i = rem & 31;
        pw2[j] = (t81 < 81) ? f2bf(prim_w[(o * 32 + i) * 81 + t81]) : (unsigned short)0;
    } else {
        const int k = tid - 111616;
        if (k < B * 16) S[k] = 0.f;
    }
}

// ---------------- main kernel ----------------
__global__ __launch_bounds__(256, 2) void caps_main(
    const float* __restrict__ x,
    const float* __restrict__ conv1_b,
    const float* __restrict__ prim_b,
    const float* __restrict__ dig_W,
    const unsigned short* __restrict__ c1wp2,
    const unsigned short* __restrict__ pw2,
    float* __restrict__ S)
{
    __shared__ __align__(16) unsigned short c1t[2 * C1TN];  // 64 KB (2 d-slices)
    __shared__ __align__(16) unsigned imgp[1344];           // bf16 pairs + zero pad
    __shared__ unsigned short offT[64];                     // byte offsets into imgp
    __shared__ float pbs[32];

    const int b = blockIdx.x >> 2, dp = blockIdx.x & 3;
    const int d0 = dp * 2;
    const int t = threadIdx.x;
    const int wave = t >> 6, lane = t & 63, quad = lane >> 4, l16 = lane & 15;

    // ---- imgp: packed bf16 pairs (img[y][x], img[y][x+1]), zero pad to 1344 ----
    const float* xb = x + b * 784;
    for (int j = t; j < 1344; j += 256) {
        unsigned v = 0;
        if (j < 784) {
            const float a = xb[j];
            const int xc = j - 28 * (int)(((unsigned)j * 37450u) >> 20);
            const float c = (xc < 27) ? xb[j + 1] : 0.f;
            v = (unsigned)f2bf(a) | ((unsigned)f2bf(c) << 16);
        }
        imgp[j] = v;
    }
    // ---- tap-offset tables (byte offsets, x4) ----
    if (t < 64) {
        int v;
        if (t < 32) {
            const int ky = t >> 2, kx = 2 * (t & 3);
            v = ky * 28 + kx;
        } else {
            const int k = t + 32;
            if (k < 72) {
                const int p = k >> 1, lo = k & 1, ky = p >> 2, kx = 2 * (p & 3) + lo;
                v = ky * 28 + kx;
            } else if (k < 81) {
                v = (k - 72) * 28 + 8;
            } else v = 784;
        }
        offT[t] = (unsigned short)(4 * v);
    }
    if (t < 32) pbs[t] = prim_b[t];
    __syncthreads();

    // hoist per-lane tap byte-offsets
    unsigned tp0[4], tp1[4], t2a[4], t2b[4];
#pragma unroll
    for (int r = 0; r < 4; ++r) {
        tp0[r] = offT[quad * 4 + r];
        tp1[r] = offT[16 + quad * 4 + r];
        t2a[r] = offT[32 + quad * 8 + 2 * r];
        t2b[r] = offT[32 + quad * 8 + 2 * r + 1];
    }

    // ======== conv1: waves 0,1 -> e=0; waves 2,3 -> e=1; mt parity split ========
    {
        const int e = wave >> 1;
        const int d = d0 + e;
        unsigned short* dst = c1t + e * C1TN;
        const float cb0 = conv1_b[l16 * 8 + d];
        const float cb1 = conv1_b[(16 + l16) * 8 + d];
        bf16x8 Bw0[3], Bw1[3];
#pragma unroll
        for (int ks = 0; ks < 3; ++ks) {
            Bw0[ks] = *(const bf16x8*)&c1wp2[(l16 * 8 + d) * 96 + ks * 32 + quad * 8];
            Bw1[ks] = *(const bf16x8*)&c1wp2[((16 + l16) * 8 + d) * 96 + ks * 32 + quad * 8];
        }
        for (int mt = (wave & 1); mt < 25; mt += 2) {
            const int pos = mt * 16 + l16;
            const int y = (int)(((unsigned)pos * 52429u) >> 20);
            const unsigned pb4 = (unsigned)(pos + 8 * y) * 4u;   // 4*(y*28+x)
            f32x4 a0 = {0.f, 0.f, 0.f, 0.f}, a1 = {0.f, 0.f, 0.f, 0.f};
            union { unsigned u[4]; bf16x8 v; } A;
#pragma unroll
            for (int r = 0; r < 4; ++r)
                A.u[r] = *(const unsigned*)((const char*)imgp + (pb4 + tp0[r]));
            a0 = __builtin_amdgcn_mfma_f32_16x16x32_bf16(A.v, Bw0[0], a0, 0, 0, 0);
            a1 = __builtin_amdgcn_mfma_f32_16x16x32_bf16(A.v, Bw1[0], a1, 0, 0, 0);
#pragma unroll
            for (int r = 0; r < 4; ++r)
                A.u[r] = *(const unsigned*)((const char*)imgp + (pb4 + tp1[r]));
            a0 = __builtin_amdgcn_mfma_f32_16x16x32_bf16(A.v, Bw0[1], a0, 0, 0, 0);
            a1 = __builtin_amdgcn_mfma_f32_16x16x32_bf16(A.v, Bw1[1], a1, 0, 0, 0);
#pragma unroll
            for (int r = 0; r < 4; ++r) {
                const unsigned lo = *(const unsigned*)((const char*)imgp + (pb4 + t2a[r]));
                const unsigned hi = *(const unsigned*)((const char*)imgp + (pb4 + t2b[r]));
                A.u[r] = (lo & 0xFFFFu) | (hi << 16);
            }
            a0 = __builtin_amdgcn_mfma_f32_16x16x32_bf16(A.v, Bw0[2], a0, 0, 0, 0);
            a1 = __builtin_amdgcn_mfma_f32_16x16x32_bf16(A.v, Bw1[2], a1, 0, 0, 0);
#pragma unroll
            for (int r = 0; r < 4; ++r) {
                const int pr = mt * 16 + quad * 4 + r;
                const int spar = (int)((((unsigned)pr * 52429u) >> 21) & 1u);
                const int base = pr * 40 + 8 * spar;
                dst[base + l16]      = f2bf(fmaxf(a0[r] + cb0, 0.f));
                dst[base + 16 + l16] = f2bf(fmaxf(a1[r] + cb1, 0.f));
            }
        }
    }
    __syncthreads();

    // ======== prim GEMM: K=32 ch per tap, 81 taps stride-4 across waves ========
    const int hp = l16 >> 3, wp = l16 & 7;               // n = 8h' + w'
    const unsigned Lbase = 80u * (unsigned)(40 * hp + 2 * wp) + 16u * quad;
    const unsigned Lh0 = Lbase + 16u * hp;               // kk=0: spar=hp
    const unsigned Lh1 = Lbase + 16u * (1 - hp);         // kk=1: spar=1-hp

    f32x4 pa[12];
#pragma unroll
    for (int q = 0; q < 12; ++q) pa[q] = (f32x4){0.f, 0.f, 0.f, 0.f};

    {
        const unsigned short* apbase = pw2 + l16 * 32 + quad * 8;
        int off = wave;
        bf16x8 A0 = *(const bf16x8*)(apbase + off * 1024);
        bf16x8 A1 = *(const bf16x8*)(apbase + off * 1024 + 512);
        for (; off < 81; off += 4) {
            const int noff = off + 4;                    // <= 84: pw2 zero-padded
            const bf16x8 nA0 = *(const bf16x8*)(apbase + noff * 1024);
            const bf16x8 nA1 = *(const bf16x8*)(apbase + noff * 1024 + 512);
            const int ky = (off * 57) >> 9;
            const int kx = off - 9 * ky;
            const int kk = (ky >> 1) & 1;
            const unsigned soff = 80u * (unsigned)(20 * ky + kx);
            const unsigned ad = (kk ? Lh1 : Lh0) + soff;
            const char* b0 = (const char*)c1t + ad;
#pragma unroll
            for (int nt = 0; nt < 3; ++nt) {
                const bf16x8 Bf0 = *(const bf16x8*)(b0 + nt * 6400);
                const bf16x8 Bf1 = *(const bf16x8*)(b0 + nt * 6400 + 2 * C1TN);
                pa[nt]     = __builtin_amdgcn_mfma_f32_16x16x32_bf16(A0, Bf0, pa[nt],     0, 0, 0);
                pa[3 + nt] = __builtin_amdgcn_mfma_f32_16x16x32_bf16(A1, Bf0, pa[3 + nt], 0, 0, 0);
                pa[6 + nt] = __builtin_amdgcn_mfma_f32_16x16x32_bf16(A0, Bf1, pa[6 + nt], 0, 0, 0);
                pa[9 + nt] = __builtin_amdgcn_mfma_f32_16x16x32_bf16(A1, Bf1, pa[9 + nt], 0, 0, 0);
            }
            A0 = nA0; A1 = nA1;
        }
    }
    __syncthreads();

    // ---- 4-wave tap reduction (redbuf overlays c1t) ----
    f32x4* redbuf = (f32x4*)c1t;
    if (wave >= 2) {
#pragma unroll
        for (int q = 0; q < 12; ++q) redbuf[((wave - 2) * 12 + q) * 64 + lane] = pa[q];
    }
    __syncthreads();
    if (wave < 2) {
#pragma unroll
        for (int q = 0; q < 12; ++q) pa[q] += redbuf[(wave * 12 + q) * 64 + lane];
        // cross-exchange: wave0 exports e1-half, wave1 exports e0-half
        if (wave == 0) {
#pragma unroll
            for (int q = 0; q < 6; ++q) redbuf[(24 + q) * 64 + lane] = pa[6 + q];
        } else {
#pragma unroll
            for (int q = 0; q < 6; ++q) redbuf[(30 + q) * 64 + lane] = pa[q];
        }
    }
    __syncthreads();

    if (wave < 2) {
        const int d = d0 + wave;
        f32x4 full[6];
#pragma unroll
        for (int q = 0; q < 6; ++q)
            full[q] = (wave == 0) ? (pa[q] + redbuf[(30 + q) * 64 + lane])
                                  : (pa[6 + q] + redbuf[(24 + q) * 64 + lane]);

        // ---- ReLU + fold u * dig_W ----
        float part[16];
#pragma unroll
        for (int k = 0; k < 16; ++k) part[k] = 0.f;

        if (wp < 6) {
#pragma unroll
            for (int mt = 0; mt < 2; ++mt)
#pragma unroll
                for (int nt = 0; nt < 3; ++nt) {
                    const f32x4 u4 = full[mt * 3 + nt];
                    const int h = 2 * nt + hp;
#pragma unroll
                    for (int r = 0; r < 4; ++r) {
                        const int o = mt * 16 + quad * 4 + r;
                        const float val = fmaxf(u4[r] + pbs[o], 0.f);
                        const int nc = o * 36 + wp * 6 + h;
                        const f32x4* wd = (const f32x4*)&dig_W[(nc * 8 + d) * 16];
#pragma unroll
                        for (int m = 0; m < 4; ++m) {
                            const f32x4 wv = wd[m];
                            part[m * 4 + 0] = fmaf(val, wv[0], part[m * 4 + 0]);
                            part[m * 4 + 1] = fmaf(val, wv[1], part[m * 4 + 1]);
                            part[m * 4 + 2] = fmaf(val, wv[2], part[m * 4 + 2]);
                            part[m * 4 + 3] = fmaf(val, wv[3], part[m * 4 + 3]);
                        }
                    }
                }
        }

#pragma unroll
        for (int k = 0; k < 16; ++k) {
            float v = part[k];
            v += __shfl_xor(v, 32, 64);
            v += __shfl_xor(v, 16, 64);
            v += __shfl_xor(v, 8, 64);
            v += __shfl_xor(v, 4, 64);
            v += __shfl_xor(v, 2, 64);
            v += __shfl_xor(v, 1, 64);
            part[k] = v;
        }
        if (lane == 0) {
#pragma unroll
            for (int k = 0; k < 16; ++k) atomicAdd(&S[b * 16 + k], part[k]);
        }
    }
}

// ---------------- epilogue kernel ----------------
__global__ void caps_epi(const float* __restrict__ S, const float* __restrict__ colsum,
                         const float* __restrict__ OW, const float* __restrict__ out_b,
                         float* __restrict__ out, int B)
{
    const int b = blockIdx.x * 256 + threadIdx.x;
    if (b >= B) return;
    float Sv[16]; float l2 = 0.f, l1 = 0.f;
#pragma unroll
    for (int k = 0; k < 16; ++k) {
        const float s = (S[b * 16 + k] + colsum[k]) * (1.f / 1152.f);
        Sv[k] = s; l2 += s * s; l1 += fabsf(s);
    }
    l2 = sqrtf(l2);
    const float sc = l2 / (1.f + l2) / l1;
    float lg[10]; float mx = -1e30f;
#pragma unroll
    for (int o = 0; o < 10; ++o) {
        float a = out_b[o];
#pragma unroll
        for (int k = 0; k < 16; ++k) a = fmaf(Sv[k] * sc, OW[o * 16 + k], a);
        lg[o] = a; mx = fmaxf(mx, a);
    }
    float sum = 0.f;
#pragma unroll
    for (int o = 0; o < 10; ++o) { lg[o] = expf(lg[o] - mx); sum += lg[o]; }
    const float inv = 1.f / sum;
#pragma unroll
    for (int o = 0; o < 10; ++o) out[b * 10 + o] = lg[o] * inv;
}

extern "C" void kernel_launch(void* const* d_in, const int* in_sizes, int n_in,
                              void* d_out, int out_size, void* d_ws, size_t ws_size,
                              hipStream_t stream) {
    const float* x       = (const float*)d_in[0];
    const float* conv1_w = (const float*)d_in[1];
    const float* conv1_b = (const float*)d_in[2];
    const float* prim_w  = (const float*)d_in[3];
    const float* prim_b  = (const float*)d_in[4];
    const float* dig_W   = (const float*)d_in[5];
    const float* dig_Wb  = (const float*)d_in[6];
    const float* out_w   = (const float*)d_in[7];
    const float* out_b   = (const float*)d_in[8];
    float* out = (float*)d_out;

    const int B = in_sizes[0] / 784;   // 512

    char* w = (char*)d_ws;
    float* S              = (float*)(w);                 // 32768 B
    float* colsum         = (float*)(w + 32768);
    float* OW             = (float*)(w + 32832);
    unsigned short* c1wp2 = (unsigned short*)(w + 33472);            // 49152 B
    unsigned short* pw2   = (unsigned short*)(w + 33472 + 49152);    // 174080 B

    caps_pre<<<469, 256, 0, stream>>>(conv1_w, prim_w, dig_Wb, out_w,
                                      S, colsum, OW, c1wp2, pw2, B);
    caps_main<<<B * 4, 256, 0, stream>>>(x, conv1_b, prim_b, dig_W, c1wp2, pw2, S);
    caps_epi<<<(B + 255) / 256, 256, 0, stream>>>(S, colsum, OW, out_b, out, B);
}